// Round 1
// baseline (15307.465 us; speedup 1.0000x reference)
//
#include <hip/hip_runtime.h>
#include <math.h>

// Model: conv-front -> encoder LSTM (L=128, H=1024) -> attention decoder (T=24)
// B=128, L=128, FEAT=36, EXTRA=12, K1=3, CONV_OUT=32, EMB=6, H=1024, A=256,
// T_OUT=24, M=151 (buf rows). Key structural optimization vs reference:
// kp = buf @ Wk^T is incrementally maintained (one new row per decoder step)
// instead of recomputed (saves ~233 GFLOP).

#define NB 128      // batch
#define NL 128      // seq len
#define NH 1024     // hidden
#define NA 256      // attn dim
#define NT 24       // T_OUT
#define NM 151      // L-1+T_OUT

__device__ __forceinline__ float sig_f(float x) {
  return 1.0f / (1.0f + __expf(-x));
}
__device__ __forceinline__ float tanh_f(float x) {
  x = fminf(9.0f, fmaxf(-9.0f, x));
  float e = __expf(2.0f * x);
  return (e - 1.0f) / (e + 1.0f);
}

// ---------------------------------------------------------------------------
// Fused conv1(softplus) -> conv2(relu) -> lin3 -> concat extras = lstm_in
// grid(NB), block(128). Conv is over W=FEAT with C=L channels (NCW layout).
// ---------------------------------------------------------------------------
__global__ __launch_bounds__(128) void conv_front(
    const float* __restrict__ x,      // (B, L, 48)
    const float* __restrict__ w1, const float* __restrict__ b1,
    const float* __restrict__ w2, const float* __restrict__ b2,
    const float* __restrict__ w3, const float* __restrict__ b3,
    float* __restrict__ lstm_in)      // (B, L, 18)
{
  int b = blockIdx.x;
  int t = threadIdx.x;                 // channel / row index 0..127
  __shared__ float d[128][36];
  __shared__ float h1[128][34];
  __shared__ float h2[128][32];

  const float* xr = x + (size_t)(b * NL + t) * 48;
  #pragma unroll
  for (int f = 0; f < 36; ++f) d[t][f] = xr[f];
  __syncthreads();

  // conv1 + softplus : out channel = t
  float acc[34];
  {
    float bias = b1[t];
    #pragma unroll
    for (int w = 0; w < 34; ++w) acc[w] = bias;
  }
  const float* wr = w1 + t * 384;      // (co, ci, k)
  for (int ci = 0; ci < 128; ++ci) {
    float row[36];
    #pragma unroll
    for (int f = 0; f < 36; ++f) row[f] = d[ci][f];
    float wa = wr[ci * 3 + 0], wb = wr[ci * 3 + 1], wc = wr[ci * 3 + 2];
    #pragma unroll
    for (int w = 0; w < 34; ++w)
      acc[w] += row[w] * wa + row[w + 1] * wb + row[w + 2] * wc;
  }
  #pragma unroll
  for (int w = 0; w < 34; ++w) {
    float z = acc[w];
    h1[t][w] = (z > 20.0f) ? z : log1pf(__expf(z));
  }
  __syncthreads();

  // conv2 + relu
  float acc2[32];
  {
    float bias = b2[t];
    #pragma unroll
    for (int w = 0; w < 32; ++w) acc2[w] = bias;
  }
  const float* wr2 = w2 + t * 384;
  for (int ci = 0; ci < 128; ++ci) {
    float row[34];
    #pragma unroll
    for (int f = 0; f < 34; ++f) row[f] = h1[ci][f];
    float wa = wr2[ci * 3 + 0], wb = wr2[ci * 3 + 1], wc = wr2[ci * 3 + 2];
    #pragma unroll
    for (int w = 0; w < 32; ++w)
      acc2[w] += row[w] * wa + row[w + 1] * wb + row[w + 2] * wc;
  }
  #pragma unroll
  for (int w = 0; w < 32; ++w) h2[t][w] = fmaxf(acc2[w], 0.0f);
  __syncthreads();

  // lin3 + concat extras; thread t = position l
  float* outr = lstm_in + (size_t)(b * NL + t) * 18;
  #pragma unroll
  for (int e = 0; e < 6; ++e) {
    float s = b3[e];
    #pragma unroll
    for (int f = 0; f < 32; ++f) s += h2[t][f] * w3[e * 32 + f];
    outr[e] = s;
  }
  #pragma unroll
  for (int j = 0; j < 12; ++j) outr[6 + j] = xr[36 + j];
}

// ---------------------------------------------------------------------------
// Generic fp32 GEMM: C[i,j] = bias[j] + sum_k A[i,:] * W(j,:)  (+ small S part)
// W(j,k) = k<k1 ? W1[j*k1+k] : W2[j*k2+(k-k1)].  M%32==0, N%64==0, K%16==0.
// grid(M/32, N/64), block(256). Each thread: 2x4 micro-tile.
// ---------------------------------------------------------------------------
__global__ __launch_bounds__(256) void gemm_f32(
    const float* __restrict__ A, int lda,
    const float* __restrict__ W1, int k1,
    const float* __restrict__ W2, int k2,
    const float* __restrict__ bias,
    const float* __restrict__ S, int ldS,
    const float* __restrict__ Ws, int ks,
    float* __restrict__ C, int ldc)
{
  __shared__ float As[16][32];
  __shared__ float Bs[16][64];
  int tid = threadIdx.x;
  int bi = blockIdx.x * 32;
  int bj = blockIdx.y * 64;
  int K = k1 + k2;

  int tr = (tid & 15) * 2;
  int tc = (tid >> 4) * 4;

  int a_row = tid >> 2;          // 0..63 (only <32 used for A)
  int a_k4  = (tid & 3) * 4;

  float acc[2][4] = {{0,0,0,0},{0,0,0,0}};

  for (int k0 = 0; k0 < K; k0 += 16) {
    if (tid < 128) {
      const float* ap = A + (size_t)(bi + a_row) * lda + k0 + a_k4;
      float4 v = *(const float4*)ap;
      As[a_k4 + 0][a_row] = v.x; As[a_k4 + 1][a_row] = v.y;
      As[a_k4 + 2][a_row] = v.z; As[a_k4 + 3][a_row] = v.w;
    }
    {
      int j = bj + a_row;
      const float* wp;
      if (k0 < k1) wp = W1 + (size_t)j * k1 + k0 + a_k4;
      else         wp = W2 + (size_t)j * k2 + (k0 - k1) + a_k4;
      float4 v = *(const float4*)wp;
      Bs[a_k4 + 0][a_row] = v.x; Bs[a_k4 + 1][a_row] = v.y;
      Bs[a_k4 + 2][a_row] = v.z; Bs[a_k4 + 3][a_row] = v.w;
    }
    __syncthreads();
    #pragma unroll
    for (int kk = 0; kk < 16; ++kk) {
      float a0 = As[kk][tr], a1 = As[kk][tr + 1];
      float4 w = *(const float4*)&Bs[kk][tc];
      acc[0][0] += a0 * w.x; acc[0][1] += a0 * w.y;
      acc[0][2] += a0 * w.z; acc[0][3] += a0 * w.w;
      acc[1][0] += a1 * w.x; acc[1][1] += a1 * w.y;
      acc[1][2] += a1 * w.z; acc[1][3] += a1 * w.w;
    }
    __syncthreads();
  }

  if (ks > 0) {
    for (int k = 0; k < ks; ++k) {
      float s0 = S[(size_t)(bi + tr) * ldS + k];
      float s1 = S[(size_t)(bi + tr + 1) * ldS + k];
      #pragma unroll
      for (int jj = 0; jj < 4; ++jj) {
        float wv = Ws[(size_t)(bj + tc + jj) * ks + k];
        acc[0][jj] += s0 * wv;
        acc[1][jj] += s1 * wv;
      }
    }
  }

  float bv[4] = {0, 0, 0, 0};
  if (bias) {
    #pragma unroll
    for (int jj = 0; jj < 4; ++jj) bv[jj] = bias[bj + tc + jj];
  }
  #pragma unroll
  for (int r = 0; r < 2; ++r) {
    #pragma unroll
    for (int jj = 0; jj < 4; ++jj)
      C[(size_t)(bi + tr + r) * ldc + bj + tc + jj] = acc[r][jj] + bv[jj];
  }
}

// ---------------------------------------------------------------------------
// LSTM cell kernels. gates layout: [i | f | g | o] each NH wide.
// ---------------------------------------------------------------------------
__device__ __forceinline__ void cell_math(const float4& gi, const float4& gf,
                                          const float4& gg, const float4& go,
                                          const float4& cv, float4& cn, float4& hn) {
  cn.x = sig_f(gf.x) * cv.x + sig_f(gi.x) * tanh_f(gg.x);
  cn.y = sig_f(gf.y) * cv.y + sig_f(gi.y) * tanh_f(gg.y);
  cn.z = sig_f(gf.z) * cv.z + sig_f(gi.z) * tanh_f(gg.z);
  cn.w = sig_f(gf.w) * cv.w + sig_f(gi.w) * tanh_f(gg.w);
  hn.x = sig_f(go.x) * tanh_f(cn.x);
  hn.y = sig_f(go.y) * tanh_f(cn.y);
  hn.z = sig_f(go.z) * tanh_f(cn.z);
  hn.w = sig_f(go.w) * tanh_f(cn.w);
}

__global__ __launch_bounds__(256) void enc_cell(
    const float* __restrict__ gates, float* __restrict__ h, float* __restrict__ c,
    float* __restrict__ buf, int t)
{
  int b = blockIdx.x;
  int j = threadIdx.x * 4;
  const float* g = gates + (size_t)b * 4096;
  float4 gi = *(const float4*)(g + j);
  float4 gf = *(const float4*)(g + 1024 + j);
  float4 gg = *(const float4*)(g + 2048 + j);
  float4 go = *(const float4*)(g + 3072 + j);
  float4 cv = *(const float4*)(c + (size_t)b * NH + j);
  float4 cn, hn;
  cell_math(gi, gf, gg, go, cv, cn, hn);
  *(float4*)(c + (size_t)b * NH + j) = cn;
  *(float4*)(h + (size_t)b * NH + j) = hn;
  *(float4*)(buf + ((size_t)(b * NM + t)) * NH + j) = hn;
}

__global__ __launch_bounds__(256) void dec_cell(
    const float* __restrict__ gates, float* __restrict__ h, float* __restrict__ c,
    float* __restrict__ buf, float* __restrict__ qbuf, float* __restrict__ Xdec,
    float* __restrict__ out, const float* __restrict__ out_w,
    const float* __restrict__ out_b, int t)
{
  __shared__ float red[256];
  int b = blockIdx.x;
  int tid = threadIdx.x;
  int j = tid * 4;
  const float* g = gates + (size_t)b * 4096;
  float4 gi = *(const float4*)(g + j);
  float4 gf = *(const float4*)(g + 1024 + j);
  float4 gg = *(const float4*)(g + 2048 + j);
  float4 go = *(const float4*)(g + 3072 + j);
  float4 cv = *(const float4*)(c + (size_t)b * NH + j);
  float4 cn, hn;
  cell_math(gi, gf, gg, go, cv, cn, hn);
  *(float4*)(c + (size_t)b * NH + j) = cn;
  *(float4*)(h + (size_t)b * NH + j) = hn;

  float4 ow = *(const float4*)(out_w + j);
  red[tid] = hn.x * ow.x + hn.y * ow.y + hn.z * ow.z + hn.w * ow.w;
  __syncthreads();
  for (int s = 128; s > 0; s >>= 1) {
    if (tid < s) red[tid] += red[tid + s];
    __syncthreads();
  }
  if (tid == 0) out[b * NT + t] = red[0] + out_b[0];

  if (t < NT - 1) {
    *(float4*)(buf + ((size_t)(b * NM + NL + t)) * NH + j) = hn;
    *(float4*)(qbuf + (size_t)(2 * b) * NH + j) = hn;
    *(float4*)(qbuf + (size_t)(2 * b + 1) * NH + j) = cn;
    *(float4*)(Xdec + (size_t)b * 3072 + 2048 + j) = hn;
  }
}

__global__ __launch_bounds__(256) void dec_prep(
    const float* __restrict__ h, const float* __restrict__ c,
    float* __restrict__ qbuf, float* __restrict__ Xdec)
{
  int b = blockIdx.x;
  int j = threadIdx.x * 4;
  float4 hv = *(const float4*)(h + (size_t)b * NH + j);
  float4 cv = *(const float4*)(c + (size_t)b * NH + j);
  *(float4*)(qbuf + (size_t)(2 * b) * NH + j) = hv;
  *(float4*)(qbuf + (size_t)(2 * b + 1) * NH + j) = cv;
  *(float4*)(Xdec + (size_t)b * 3072 + 2048 + j) = hv;
}

__global__ __launch_bounds__(256) void init_hc(float* __restrict__ h, float* __restrict__ c) {
  int i = (blockIdx.x * 256 + threadIdx.x) * 4;
  float4 z = {0, 0, 0, 0};
  *(float4*)(h + i) = z;
  *(float4*)(c + i) = z;
}

// ---------------------------------------------------------------------------
// Attention: scores(b,n,m) = sum_a tanh(qp[b,n,a]+kp[b,m,a])*Wv[a]; softmax
// over n (pairwise); ctx[b,n,:] = sum_m w * buf[b,m,:]. grid(NB), block(256).
// ---------------------------------------------------------------------------
__global__ __launch_bounds__(256) void attn_kernel(
    const float* __restrict__ qp, const float* __restrict__ kp,
    const float* __restrict__ buf, const float* __restrict__ Wv,
    float* __restrict__ Xdec, int t)
{
  int b = blockIdx.x;
  int tid = threadIdx.x;
  int Mt = NL + t;   // rows 0 .. 127+t valid
  __shared__ float sWv[256], q0[256], q1[256];
  __shared__ float sc[2][NM + 1];
  __shared__ float w0s[NM + 1], w1s[NM + 1];
  sWv[tid] = Wv[tid];
  q0[tid] = qp[(size_t)(2 * b) * NA + tid];
  q1[tid] = qp[(size_t)(2 * b + 1) * NA + tid];
  __syncthreads();

  for (int idx = tid; idx < 2 * Mt; idx += 256) {
    int m = idx >> 1, n = idx & 1;
    const float* q = n ? q1 : q0;
    const float* kpr = kp + (size_t)(b * NM + m) * NA;
    float s = 0.0f;
    for (int a = 0; a < NA; ++a) s += tanh_f(q[a] + kpr[a]) * sWv[a];
    sc[n][m] = s;
  }
  __syncthreads();
  for (int m = tid; m < Mt; m += 256) {
    float s0 = sc[0][m], s1 = sc[1][m];
    float mx = fmaxf(s0, s1);
    float e0 = __expf(s0 - mx), e1 = __expf(s1 - mx);
    float inv = 1.0f / (e0 + e1);
    w0s[m] = e0 * inv;
    w1s[m] = e1 * inv;
  }
  __syncthreads();

  float4 a0 = {0, 0, 0, 0}, a1 = {0, 0, 0, 0};
  const float* bb = buf + (size_t)b * NM * NH + tid * 4;
  for (int m = 0; m < Mt; ++m) {
    float4 v = *(const float4*)(bb + (size_t)m * NH);
    float w0 = w0s[m], w1 = w1s[m];
    a0.x += v.x * w0; a0.y += v.y * w0; a0.z += v.z * w0; a0.w += v.w * w0;
    a1.x += v.x * w1; a1.y += v.y * w1; a1.z += v.z * w1; a1.w += v.w * w1;
  }
  *(float4*)(Xdec + (size_t)b * 3072 + tid * 4) = a0;
  *(float4*)(Xdec + (size_t)b * 3072 + 1024 + tid * 4) = a1;
}

// ---------------------------------------------------------------------------
extern "C" void kernel_launch(void* const* d_in, const int* in_sizes, int n_in,
                              void* d_out, int out_size, void* d_ws, size_t ws_size,
                              hipStream_t stream) {
  const float* x       = (const float*)d_in[0];
  const float* conv1_w = (const float*)d_in[1];
  const float* conv1_b = (const float*)d_in[2];
  const float* conv2_w = (const float*)d_in[3];
  const float* conv2_b = (const float*)d_in[4];
  const float* lin3_w  = (const float*)d_in[5];
  const float* lin3_b  = (const float*)d_in[6];
  const float* enc_Wih = (const float*)d_in[7];
  const float* enc_Whh = (const float*)d_in[8];
  const float* enc_b   = (const float*)d_in[9];
  const float* attn_Wq = (const float*)d_in[10];
  const float* attn_Wk = (const float*)d_in[11];
  const float* attn_Wv = (const float*)d_in[12];
  const float* dec_Wih = (const float*)d_in[13];
  const float* dec_Whh = (const float*)d_in[14];
  const float* dec_b   = (const float*)d_in[15];
  const float* out_w   = (const float*)d_in[16];
  const float* out_b   = (const float*)d_in[17];
  float* out = (float*)d_out;

  float* ws = (float*)d_ws;
  float* buf     = ws;                       // NB*NM*NH      = 19,791,872
  float* kp      = buf + (size_t)NB * NM * NH;      // NB*NM*NA = 4,947,968
  float* lstm_in = kp + (size_t)NB * NM * NA;       // NB*NL*18 = 294,912
  float* gates   = lstm_in + (size_t)NB * NL * 18;  // NB*4096  = 524,288
  float* h       = gates + (size_t)NB * 4096;       // NB*NH
  float* c       = h + (size_t)NB * NH;
  float* qbuf    = c + (size_t)NB * NH;             // NB*2*NH
  float* qp      = qbuf + (size_t)NB * 2 * NH;      // NB*2*NA
  float* Xdec    = qp + (size_t)NB * 2 * NA;        // NB*3072
  // total ~106 MB

  init_hc<<<128, 256, 0, stream>>>(h, c);
  conv_front<<<NB, 128, 0, stream>>>(x, conv1_w, conv1_b, conv2_w, conv2_b,
                                     lin3_w, lin3_b, lstm_in);

  // Encoder: 128 sequential steps
  for (int t = 0; t < NL; ++t) {
    gemm_f32<<<dim3(4, 64), 256, 0, stream>>>(
        h, NH, enc_Whh, NH, nullptr, 0, enc_b,
        lstm_in + t * 18, NL * 18, enc_Wih, 18, gates, 4096);
    enc_cell<<<NB, 256, 0, stream>>>(gates, h, c, buf, t);
  }

  // kp for all buf rows (rows >=128 are poison; overwritten before use)
  gemm_f32<<<dim3(NB * NM / 32, NA / 64), 256, 0, stream>>>(
      buf, NH, attn_Wk, NH, nullptr, 0, nullptr,
      nullptr, 0, nullptr, 0, kp, NA);

  dec_prep<<<NB, 256, 0, stream>>>(h, c, qbuf, Xdec);

  // Decoder: 24 sequential steps
  for (int t = 0; t < NT; ++t) {
    gemm_f32<<<dim3(8, 4), 256, 0, stream>>>(
        qbuf, NH, attn_Wq, NH, nullptr, 0, nullptr,
        nullptr, 0, nullptr, 0, qp, NA);
    attn_kernel<<<NB, 256, 0, stream>>>(qp, kp, buf, attn_Wv, Xdec, t);
    gemm_f32<<<dim3(4, 64), 256, 0, stream>>>(
        Xdec, 3072, dec_Wih, 2048, dec_Whh, NH, dec_b,
        nullptr, 0, nullptr, 0, gates, 4096);
    dec_cell<<<NB, 256, 0, stream>>>(gates, h, c, buf, qbuf, Xdec,
                                     out, out_w, out_b, t);
    if (t < NT - 1) {
      // kp row for the newly appended buf row (NL + t)
      gemm_f32<<<dim3(4, 4), 256, 0, stream>>>(
          h, NH, attn_Wk, NH, nullptr, 0, nullptr,
          nullptr, 0, nullptr, 0, kp + (size_t)(NL + t) * NA, NM * NA);
    }
  }
}

// Round 6
// 9389.476 us; speedup vs baseline: 1.6303x; 1.6303x over previous
//
#include <hip/hip_runtime.h>
#include <math.h>

// Round 6: buf stored as INT16 fixed-point (|h|<1 strictly; err <= 1.53e-5,
// 13-64x better than bf16 at same 2 B/elem). Evidence: round-5 SR experiment
// showed output err scales linearly with buf quantization amplitude (2.04x
// for SR's 2x rms) => buf storage error dominates; i16 divides it by >10.
// SR reverted to RN. Encoder h recurrence uses dedicated bf16 hi/lo ping-pong
// (overlaid on encoder-dead Wdx region). ws total unchanged: 106,102,784 B.

#define NB 128
#define NL 128
#define NH 1024
#define NA 256
#define NT 24
#define NM 151

typedef __attribute__((ext_vector_type(8))) short bf16x8;
typedef __attribute__((ext_vector_type(8))) short s16x8;
typedef __attribute__((ext_vector_type(4))) float f32x4;

#define MFMA(a, b, acc) __builtin_amdgcn_mfma_f32_16x16x32_bf16(a, b, acc, 0, 0, 0)

#define I16_SCALE 32767.0f
#define I16_INV   (1.0f / 32767.0f)

__device__ __forceinline__ float sig_f(float x) {
  return 1.0f / (1.0f + __expf(-x));
}
__device__ __forceinline__ float tanh_f(float x) {
  x = fminf(9.0f, fmaxf(-9.0f, x));
  float e = __expf(2.0f * x);
  return (e - 1.0f) / (e + 1.0f);
}
__device__ __forceinline__ unsigned short f2bf(float f) {
  unsigned int u = __float_as_uint(f);
  u = (u + 0x7FFFu + ((u >> 16) & 1u)) >> 16;
  return (unsigned short)u;
}
__device__ __forceinline__ float bf2f(unsigned short u) {
  return __uint_as_float(((unsigned int)u) << 16);
}
__device__ __forceinline__ short f2i16(float f) {
  return (short)__float2int_rn(f * I16_SCALE);
}

// ---------------------------------------------------------------------------
// conv front (proven round 1)
// ---------------------------------------------------------------------------
__global__ __launch_bounds__(128) void conv_front(
    const float* __restrict__ x,
    const float* __restrict__ w1, const float* __restrict__ b1,
    const float* __restrict__ w2, const float* __restrict__ b2,
    const float* __restrict__ w3, const float* __restrict__ b3,
    float* __restrict__ lstm_in)
{
  int b = blockIdx.x;
  int t = threadIdx.x;
  __shared__ float d[128][36];
  __shared__ float h1[128][34];
  __shared__ float h2[128][32];

  const float* xr = x + (size_t)(b * NL + t) * 48;
  #pragma unroll
  for (int f = 0; f < 36; ++f) d[t][f] = xr[f];
  __syncthreads();

  float acc[34];
  {
    float bias = b1[t];
    #pragma unroll
    for (int w = 0; w < 34; ++w) acc[w] = bias;
  }
  const float* wr = w1 + t * 384;
  for (int ci = 0; ci < 128; ++ci) {
    float row[36];
    #pragma unroll
    for (int f = 0; f < 36; ++f) row[f] = d[ci][f];
    float wa = wr[ci * 3 + 0], wb = wr[ci * 3 + 1], wc = wr[ci * 3 + 2];
    #pragma unroll
    for (int w = 0; w < 34; ++w)
      acc[w] += row[w] * wa + row[w + 1] * wb + row[w + 2] * wc;
  }
  #pragma unroll
  for (int w = 0; w < 34; ++w) {
    float z = acc[w];
    h1[t][w] = (z > 20.0f) ? z : log1pf(__expf(z));
  }
  __syncthreads();

  float acc2[32];
  {
    float bias = b2[t];
    #pragma unroll
    for (int w = 0; w < 32; ++w) acc2[w] = bias;
  }
  const float* wr2 = w2 + t * 384;
  for (int ci = 0; ci < 128; ++ci) {
    float row[34];
    #pragma unroll
    for (int f = 0; f < 34; ++f) row[f] = h1[ci][f];
    float wa = wr2[ci * 3 + 0], wb = wr2[ci * 3 + 1], wc = wr2[ci * 3 + 2];
    #pragma unroll
    for (int w = 0; w < 32; ++w)
      acc2[w] += row[w] * wa + row[w + 1] * wb + row[w + 2] * wc;
  }
  #pragma unroll
  for (int w = 0; w < 32; ++w) h2[t][w] = fmaxf(acc2[w], 0.0f);
  __syncthreads();

  float* outr = lstm_in + (size_t)(b * NL + t) * 18;
  #pragma unroll
  for (int e = 0; e < 6; ++e) {
    float s = b3[e];
    #pragma unroll
    for (int f = 0; f < 32; ++f) s += h2[t][f] * w3[e * 32 + f];
    outr[e] = s;
  }
  #pragma unroll
  for (int j = 0; j < 12; ++j) outr[6 + j] = xr[36 + j];
}

// ---------------------------------------------------------------------------
// conversion / init
// ---------------------------------------------------------------------------
__global__ void split_bf(const float* __restrict__ src,
                         unsigned short* __restrict__ hi,
                         unsigned short* __restrict__ lo, int n) {
  int i = blockIdx.x * 256 + threadIdx.x;
  if (i < n) {
    float v = src[i];
    unsigned short h = f2bf(v);
    hi[i] = h;
    lo[i] = f2bf(v - bf2f(h));
  }
}

__global__ void init_all(float* __restrict__ c,
                         unsigned short* __restrict__ hhi0,
                         unsigned short* __restrict__ hlo0,
                         float* __restrict__ out) {
  int i = blockIdx.x * 256 + threadIdx.x;
  if (i < NB * NH) { c[i] = 0.0f; hhi0[i] = 0; hlo0[i] = 0; }
  if (i < NB * NT) out[i] = 0.0f;
}

// ---------------------------------------------------------------------------
// Encoder step: gates = h@Whh^T (split 3-term) + x@Wih^T (fp32 scalar) + b.
// h carried as dedicated bf16 hi/lo ping-pong (fp32-faithful recurrence).
// buf row t written as i16. Block k owns gate cols c0..c0+7 of i/f/g/o.
// ---------------------------------------------------------------------------
__global__ __launch_bounds__(256) void enc_step(
    const unsigned short* __restrict__ hhi_in,
    const unsigned short* __restrict__ hlo_in,
    unsigned short* __restrict__ hhi_out,
    unsigned short* __restrict__ hlo_out,
    const unsigned short* __restrict__ Whh_hi,
    const unsigned short* __restrict__ Whh_lo,
    const float* __restrict__ Wih,
    const float* __restrict__ encb,
    const float* __restrict__ lstm_in,
    float* __restrict__ c,
    short* __restrict__ buf,                 // [B,NM,NH] i16
    int t)
{
  __shared__ float G[128][33];
  int tid = threadIdx.x;
  int w = tid >> 6, lane = tid & 63;
  int l15 = lane & 15, q8 = (lane >> 4) * 8, q4 = (lane >> 4) * 4;
  int c0 = blockIdx.x * 8;

  int idx0 = l15;
  int idx1 = 16 + l15;
  size_t grow0 = (size_t)((idx0 >> 3) * NH + c0 + (idx0 & 7)) * NH;
  size_t grow1 = (size_t)((idx1 >> 3) * NH + c0 + (idx1 & 7)) * NH;
  const unsigned short* B0h = Whh_hi + grow0;
  const unsigned short* B1h = Whh_hi + grow1;
  const unsigned short* B0l = Whh_lo + grow0;
  const unsigned short* B1l = Whh_lo + grow1;
  size_t ar0 = (size_t)(32 * w + l15) * NH;
  size_t ar1 = (size_t)(32 * w + 16 + l15) * NH;
  const unsigned short* A0h = hhi_in + ar0;
  const unsigned short* A1h = hhi_in + ar1;
  const unsigned short* A0l = hlo_in + ar0;
  const unsigned short* A1l = hlo_in + ar1;

  f32x4 a00 = {0,0,0,0}, a01 = {0,0,0,0}, a10 = {0,0,0,0}, a11 = {0,0,0,0};
  for (int k0 = 0; k0 < NH; k0 += 32) {
    int ko = k0 + q8;
    bf16x8 x0h = *(const bf16x8*)(A0h + ko);
    bf16x8 x0l = *(const bf16x8*)(A0l + ko);
    bf16x8 x1h = *(const bf16x8*)(A1h + ko);
    bf16x8 x1l = *(const bf16x8*)(A1l + ko);
    bf16x8 y0h = *(const bf16x8*)(B0h + ko);
    bf16x8 y0l = *(const bf16x8*)(B0l + ko);
    bf16x8 y1h = *(const bf16x8*)(B1h + ko);
    bf16x8 y1l = *(const bf16x8*)(B1l + ko);
    a00 = MFMA(x0h, y0h, a00); a00 = MFMA(x0l, y0h, a00); a00 = MFMA(x0h, y0l, a00);
    a01 = MFMA(x0h, y1h, a01); a01 = MFMA(x0l, y1h, a01); a01 = MFMA(x0h, y1l, a01);
    a10 = MFMA(x1h, y0h, a10); a10 = MFMA(x1l, y0h, a10); a10 = MFMA(x1h, y0l, a10);
    a11 = MFMA(x1h, y1h, a11); a11 = MFMA(x1l, y1h, a11); a11 = MFMA(x1h, y1l, a11);
  }
  #pragma unroll
  for (int r = 0; r < 4; ++r) {
    G[32 * w + q4 + r][l15]           = a00[r];
    G[32 * w + q4 + r][16 + l15]      = a01[r];
    G[32 * w + 16 + q4 + r][l15]      = a10[r];
    G[32 * w + 16 + q4 + r][16 + l15] = a11[r];
  }
  __syncthreads();

  int b = tid >> 1;
  int cc0 = (tid & 1) * 4;
  float4 cold = *(const float4*)(c + (size_t)b * NH + c0 + cc0);
  const float* lx = lstm_in + (size_t)(b * NL + t) * 18;
  float lxv[18];
  #pragma unroll
  for (int f = 0; f < 18; ++f) lxv[f] = lx[f];

  float rc[4], rh[4];
  #pragma unroll
  for (int j = 0; j < 4; ++j) {
    int cc = cc0 + j;
    float gate[4];
    #pragma unroll
    for (int q = 0; q < 4; ++q) {
      int row = q * NH + c0 + cc;
      float s = encb[row];
      const float* wr = Wih + (size_t)row * 18;
      #pragma unroll
      for (int f = 0; f < 18; ++f) s += lxv[f] * wr[f];
      gate[q] = G[b][q * 8 + cc] + s;
    }
    float co = (&cold.x)[j];
    float cn = sig_f(gate[1]) * co + sig_f(gate[0]) * tanh_f(gate[2]);
    float hn = sig_f(gate[3]) * tanh_f(cn);
    rc[j] = cn; rh[j] = hn;
  }
  *(float4*)(c + (size_t)b * NH + c0 + cc0) =
      make_float4(rc[0], rc[1], rc[2], rc[3]);
  unsigned short hh[4], hl[4];
  short hq[4];
  #pragma unroll
  for (int j = 0; j < 4; ++j) {
    hh[j] = f2bf(rh[j]);
    hl[j] = f2bf(rh[j] - bf2f(hh[j]));
    hq[j] = f2i16(rh[j]);
  }
  size_t hoff = (size_t)b * NH + c0 + cc0;
  *(ushort4*)(hhi_out + hoff) = make_ushort4(hh[0], hh[1], hh[2], hh[3]);
  *(ushort4*)(hlo_out + hoff) = make_ushort4(hl[0], hl[1], hl[2], hl[3]);
  *(short4*)(buf + (size_t)(b * NM + t) * NH + c0 + cc0) =
      make_short4(hq[0], hq[1], hq[2], hq[3]);
}

// ---------------------------------------------------------------------------
// Decoder step: gates = ctx@Wdx^T (split 3-term, K=2048)
//                     + h@Wdh^T (split 3-term, K=1024) + b; cell; y.
// ---------------------------------------------------------------------------
__global__ __launch_bounds__(256) void dec_step(
    const unsigned short* __restrict__ Xhi,     // [128,2048] ctx hi
    const unsigned short* __restrict__ Xlo,     // [128,2048] ctx lo
    const unsigned short* __restrict__ qin_hi,  // [256,1024] rows 2b=h,2b+1=c
    const unsigned short* __restrict__ qin_lo,
    unsigned short* __restrict__ qout_hi,
    unsigned short* __restrict__ qout_lo,
    const unsigned short* __restrict__ Wdx_hi,  // [4096,2048]
    const unsigned short* __restrict__ Wdx_lo,
    const unsigned short* __restrict__ Wdh_hi,  // [4096,1024]
    const unsigned short* __restrict__ Wdh_lo,
    const float* __restrict__ decb,
    float* __restrict__ c,
    short* __restrict__ buf,                    // i16
    const float* __restrict__ out_w, const float* __restrict__ out_b,
    float* __restrict__ out, int t)
{
  __shared__ float G[128][33];
  int tid = threadIdx.x;
  int w = tid >> 6, lane = tid & 63;
  int l15 = lane & 15, q8 = (lane >> 4) * 8, q4 = (lane >> 4) * 4;
  int c0 = blockIdx.x * 8;

  int idx0 = l15, idx1 = 16 + l15;
  size_t gr0 = (size_t)((idx0 >> 3) * NH + c0 + (idx0 & 7));
  size_t gr1 = (size_t)((idx1 >> 3) * NH + c0 + (idx1 & 7));

  f32x4 a00 = {0,0,0,0}, a01 = {0,0,0,0}, a10 = {0,0,0,0}, a11 = {0,0,0,0};

  // phase 1: ctx (split 3-term), K=2048
  {
    size_t xr0 = (size_t)(32 * w + l15) * 2048;
    size_t xr1 = (size_t)(32 * w + 16 + l15) * 2048;
    const unsigned short* X0h = Xhi + xr0;
    const unsigned short* X1h = Xhi + xr1;
    const unsigned short* X0l = Xlo + xr0;
    const unsigned short* X1l = Xlo + xr1;
    const unsigned short* W0h = Wdx_hi + gr0 * 2048;
    const unsigned short* W1h = Wdx_hi + gr1 * 2048;
    const unsigned short* W0l = Wdx_lo + gr0 * 2048;
    const unsigned short* W1l = Wdx_lo + gr1 * 2048;
    for (int k0 = 0; k0 < 2048; k0 += 32) {
      int ko = k0 + q8;
      bf16x8 x0h = *(const bf16x8*)(X0h + ko);
      bf16x8 x0l = *(const bf16x8*)(X0l + ko);
      bf16x8 x1h = *(const bf16x8*)(X1h + ko);
      bf16x8 x1l = *(const bf16x8*)(X1l + ko);
      bf16x8 y0h = *(const bf16x8*)(W0h + ko);
      bf16x8 y0l = *(const bf16x8*)(W0l + ko);
      bf16x8 y1h = *(const bf16x8*)(W1h + ko);
      bf16x8 y1l = *(const bf16x8*)(W1l + ko);
      a00 = MFMA(x0h, y0h, a00); a00 = MFMA(x0l, y0h, a00); a00 = MFMA(x0h, y0l, a00);
      a01 = MFMA(x0h, y1h, a01); a01 = MFMA(x0l, y1h, a01); a01 = MFMA(x0h, y1l, a01);
      a10 = MFMA(x1h, y0h, a10); a10 = MFMA(x1l, y0h, a10); a10 = MFMA(x1h, y0l, a10);
      a11 = MFMA(x1h, y1h, a11); a11 = MFMA(x1l, y1h, a11); a11 = MFMA(x1h, y1l, a11);
    }
  }
  // phase 2: h (split 3-term), K=1024
  {
    size_t ar0 = (size_t)(2 * (32 * w + l15)) * NH;
    size_t ar1 = (size_t)(2 * (32 * w + 16 + l15)) * NH;
    const unsigned short* A0h = qin_hi + ar0;
    const unsigned short* A1h = qin_hi + ar1;
    const unsigned short* A0l = qin_lo + ar0;
    const unsigned short* A1l = qin_lo + ar1;
    const unsigned short* B0h = Wdh_hi + gr0 * NH;
    const unsigned short* B1h = Wdh_hi + gr1 * NH;
    const unsigned short* B0l = Wdh_lo + gr0 * NH;
    const unsigned short* B1l = Wdh_lo + gr1 * NH;
    for (int k0 = 0; k0 < NH; k0 += 32) {
      int ko = k0 + q8;
      bf16x8 x0h = *(const bf16x8*)(A0h + ko);
      bf16x8 x0l = *(const bf16x8*)(A0l + ko);
      bf16x8 x1h = *(const bf16x8*)(A1h + ko);
      bf16x8 x1l = *(const bf16x8*)(A1l + ko);
      bf16x8 y0h = *(const bf16x8*)(B0h + ko);
      bf16x8 y0l = *(const bf16x8*)(B0l + ko);
      bf16x8 y1h = *(const bf16x8*)(B1h + ko);
      bf16x8 y1l = *(const bf16x8*)(B1l + ko);
      a00 = MFMA(x0h, y0h, a00); a00 = MFMA(x0l, y0h, a00); a00 = MFMA(x0h, y0l, a00);
      a01 = MFMA(x0h, y1h, a01); a01 = MFMA(x0l, y1h, a01); a01 = MFMA(x0h, y1l, a01);
      a10 = MFMA(x1h, y0h, a10); a10 = MFMA(x1l, y0h, a10); a10 = MFMA(x1h, y0l, a10);
      a11 = MFMA(x1h, y1h, a11); a11 = MFMA(x1l, y1h, a11); a11 = MFMA(x1h, y1l, a11);
    }
  }
  #pragma unroll
  for (int r = 0; r < 4; ++r) {
    G[32 * w + q4 + r][l15]           = a00[r];
    G[32 * w + q4 + r][16 + l15]      = a01[r];
    G[32 * w + 16 + q4 + r][l15]      = a10[r];
    G[32 * w + 16 + q4 + r][16 + l15] = a11[r];
  }
  __syncthreads();

  int b = tid >> 1;
  int cc0 = (tid & 1) * 4;
  float4 cold = *(const float4*)(c + (size_t)b * NH + c0 + cc0);
  float rc[4], rh[4];
  #pragma unroll
  for (int j = 0; j < 4; ++j) {
    int cc = cc0 + j;
    float gate[4];
    #pragma unroll
    for (int q = 0; q < 4; ++q)
      gate[q] = G[b][q * 8 + cc] + decb[q * NH + c0 + cc];
    float co = (&cold.x)[j];
    float cn = sig_f(gate[1]) * co + sig_f(gate[0]) * tanh_f(gate[2]);
    float hn = sig_f(gate[3]) * tanh_f(cn);
    rc[j] = cn; rh[j] = hn;
  }
  *(float4*)(c + (size_t)b * NH + c0 + cc0) =
      make_float4(rc[0], rc[1], rc[2], rc[3]);

  float py = 0.0f;
  #pragma unroll
  for (int j = 0; j < 4; ++j) py += rh[j] * out_w[c0 + cc0 + j];
  if (blockIdx.x == 0 && (tid & 1) == 0) py += out_b[0];
  atomicAdd(&out[b * NT + t], py);

  if (t < NT - 1) {
    unsigned short hh[4], hl[4], ch[4], cl[4];
    short hq[4];
    #pragma unroll
    for (int j = 0; j < 4; ++j) {
      hh[j] = f2bf(rh[j]); hl[j] = f2bf(rh[j] - bf2f(hh[j]));
      ch[j] = f2bf(rc[j]); cl[j] = f2bf(rc[j] - bf2f(ch[j]));
      hq[j] = f2i16(rh[j]);
    }
    *(short4*)(buf + (size_t)(b * NM + NL + t) * NH + c0 + cc0) =
        make_short4(hq[0], hq[1], hq[2], hq[3]);
    size_t qh = (size_t)(2 * b) * NH + c0 + cc0;
    size_t qc = (size_t)(2 * b + 1) * NH + c0 + cc0;
    *(ushort4*)(qout_hi + qh) = make_ushort4(hh[0], hh[1], hh[2], hh[3]);
    *(ushort4*)(qout_lo + qh) = make_ushort4(hl[0], hl[1], hl[2], hl[3]);
    *(ushort4*)(qout_hi + qc) = make_ushort4(ch[0], ch[1], ch[2], ch[3]);
    *(ushort4*)(qout_lo + qc) = make_ushort4(cl[0], cl[1], cl[2], cl[3]);
  }
}

// dec_prep: h from dedicated hi/lo buffers, c fp32 -> q rows.
__global__ __launch_bounds__(256) void dec_prep(
    const unsigned short* __restrict__ hhi,
    const unsigned short* __restrict__ hlo,
    const float* __restrict__ c,
    unsigned short* __restrict__ qhi, unsigned short* __restrict__ qlo)
{
  int b = blockIdx.x;
  int j = threadIdx.x * 4;
  ushort4 hv = *(const ushort4*)(hhi + (size_t)b * NH + j);
  ushort4 lv = *(const ushort4*)(hlo + (size_t)b * NH + j);
  float4 cv = *(const float4*)(c + (size_t)b * NH + j);
  unsigned short ch[4], cl[4];
  float cf[4] = {cv.x, cv.y, cv.z, cv.w};
  #pragma unroll
  for (int k = 0; k < 4; ++k) {
    ch[k] = f2bf(cf[k]); cl[k] = f2bf(cf[k] - bf2f(ch[k]));
  }
  *(ushort4*)(qhi + (size_t)(2 * b) * NH + j) = hv;
  *(ushort4*)(qlo + (size_t)(2 * b) * NH + j) = lv;
  *(ushort4*)(qhi + (size_t)(2 * b + 1) * NH + j) = make_ushort4(ch[0], ch[1], ch[2], ch[3]);
  *(ushort4*)(qlo + (size_t)(2 * b + 1) * NH + j) = make_ushort4(cl[0], cl[1], cl[2], cl[3]);
}

// ---------------------------------------------------------------------------
// q/k projections, split 3-term: qkout[256,512] = qbuf[256,1024] @ Wqk^T.
// ---------------------------------------------------------------------------
__global__ __launch_bounds__(256) void gemm_qk(
    const unsigned short* __restrict__ Ahi, const unsigned short* __restrict__ Alo,
    const unsigned short* __restrict__ Bhi, const unsigned short* __restrict__ Blo,
    float* __restrict__ C)
{
  int tid = threadIdx.x;
  int w = tid >> 6, lane = tid & 63;
  int l15 = lane & 15, q8 = (lane >> 4) * 8, q4 = (lane >> 4) * 4;
  size_t m0 = (size_t)blockIdx.x * 64;
  int n0 = blockIdx.y * 64 + w * 16;

  const unsigned short* Bh = Bhi + (size_t)(n0 + l15) * NH;
  const unsigned short* Bl = Blo + (size_t)(n0 + l15) * NH;
  f32x4 acc[4] = {{0,0,0,0},{0,0,0,0},{0,0,0,0},{0,0,0,0}};
  for (int k0 = 0; k0 < NH; k0 += 32) {
    int ko = k0 + q8;
    bf16x8 bh = *(const bf16x8*)(Bh + ko);
    bf16x8 bl = *(const bf16x8*)(Bl + ko);
    #pragma unroll
    for (int i = 0; i < 4; ++i) {
      size_t ar = (m0 + 16 * i + l15) * (size_t)NH;
      bf16x8 ah = *(const bf16x8*)(Ahi + ar + ko);
      bf16x8 al = *(const bf16x8*)(Alo + ar + ko);
      acc[i] = MFMA(ah, bh, acc[i]);
      acc[i] = MFMA(al, bh, acc[i]);
      acc[i] = MFMA(ah, bl, acc[i]);
    }
  }
  #pragma unroll
  for (int i = 0; i < 4; ++i)
    #pragma unroll
    for (int r = 0; r < 4; ++r)
      C[(m0 + 16 * i + q4 + r) * 512 + n0 + l15] = acc[i][r];
}

// ---------------------------------------------------------------------------
// Bulk kp: kp[NB*NM,256] = buf(i16) @ Wk^T. A converted i16->bf16 hi/lo in
// registers; 3-term MFMA (Ahi*Bh + Alo*Bh + Ahi*Bl). grid(302,4). One-shot.
// ---------------------------------------------------------------------------
__global__ __launch_bounds__(256) void gemm_kp(
    const short* __restrict__ A,
    const unsigned short* __restrict__ Bhi,
    const unsigned short* __restrict__ Blo,
    unsigned short* __restrict__ C)
{
  int tid = threadIdx.x;
  int w = tid >> 6, lane = tid & 63;
  int l15 = lane & 15, q8 = (lane >> 4) * 8, q4 = (lane >> 4) * 4;
  size_t m0 = (size_t)blockIdx.x * 64;
  int n0 = blockIdx.y * 64 + w * 16;

  const unsigned short* Bh = Bhi + (size_t)(n0 + l15) * NH;
  const unsigned short* Bl = Blo + (size_t)(n0 + l15) * NH;
  f32x4 acc[4] = {{0,0,0,0},{0,0,0,0},{0,0,0,0},{0,0,0,0}};
  for (int k0 = 0; k0 < NH; k0 += 32) {
    int ko = k0 + q8;
    bf16x8 bh = *(const bf16x8*)(Bh + ko);
    bf16x8 bl = *(const bf16x8*)(Bl + ko);
    #pragma unroll
    for (int i = 0; i < 4; ++i) {
      s16x8 av = *(const s16x8*)(A + (m0 + 16 * i + l15) * (size_t)NH + ko);
      bf16x8 ah, al;
      #pragma unroll
      for (int k = 0; k < 8; ++k) {
        float f = (float)av[k] * I16_INV;
        unsigned short hh = f2bf(f);
        ah[k] = (short)hh;
        al[k] = (short)f2bf(f - bf2f(hh));
      }
      acc[i] = MFMA(ah, bh, acc[i]);
      acc[i] = MFMA(al, bh, acc[i]);
      acc[i] = MFMA(ah, bl, acc[i]);
    }
  }
  #pragma unroll
  for (int i = 0; i < 4; ++i)
    #pragma unroll
    for (int r = 0; r < 4; ++r)
      C[(m0 + 16 * i + q4 + r) * NA + n0 + l15] = f2bf(acc[i][r]);
}

// ---------------------------------------------------------------------------
// Attention: scores + pairwise softmax over n; ctx accumulated fp32 from i16
// buf; written as hi/lo bf16 split to Xc. Fresh kp row stored bf16.
// ---------------------------------------------------------------------------
__global__ __launch_bounds__(256) void attn_kernel(
    const float* __restrict__ qkout,
    unsigned short* __restrict__ kp,
    const short* __restrict__ buf,            // i16
    const float* __restrict__ Wv,
    unsigned short* __restrict__ Xhi,
    unsigned short* __restrict__ Xlo,
    int t)
{
  int b = blockIdx.x;
  int tid = threadIdx.x;
  int Mt = NL + t;
  __shared__ float sWv[256], q0[256], q1[256], kNew[256];
  __shared__ float sc[2][NM + 1];
  __shared__ float w0s[NM + 1], w1s[NM + 1];
  sWv[tid] = Wv[tid];
  q0[tid] = qkout[(size_t)(2 * b) * 512 + tid];
  q1[tid] = qkout[(size_t)(2 * b + 1) * 512 + tid];
  float kn = qkout[(size_t)(2 * b) * 512 + 256 + tid];
  kNew[tid] = kn;
  kp[((size_t)(b * NM) + (NL - 1 + t)) * NA + tid] = f2bf(kn);
  __syncthreads();

  for (int idx = tid; idx < 2 * Mt; idx += 256) {
    int m = idx >> 1, n = idx & 1;
    const float* q = n ? q1 : q0;
    float s = 0.0f;
    if (m == Mt - 1) {
      for (int a = 0; a < NA; ++a) s += tanh_f(q[a] + kNew[a]) * sWv[a];
    } else {
      const unsigned short* kpr = kp + ((size_t)(b * NM) + m) * NA;
      for (int a = 0; a < NA; ++a) s += tanh_f(q[a] + bf2f(kpr[a])) * sWv[a];
    }
    sc[n][m] = s;
  }
  __syncthreads();
  for (int m = tid; m < Mt; m += 256) {
    float s0 = sc[0][m], s1 = sc[1][m];
    float mx = fmaxf(s0, s1);
    float e0 = __expf(s0 - mx), e1 = __expf(s1 - mx);
    float inv = 1.0f / (e0 + e1);
    w0s[m] = e0 * inv;
    w1s[m] = e1 * inv;
  }
  __syncthreads();

  float4 a0 = {0, 0, 0, 0}, a1 = {0, 0, 0, 0};
  const short* bb = buf + ((size_t)b * NM) * NH + tid * 4;
  for (int m = 0; m < Mt; ++m) {
    short4 v = *(const short4*)(bb + (size_t)m * NH);
    float vx = (float)v.x * I16_INV, vy = (float)v.y * I16_INV;
    float vz = (float)v.z * I16_INV, vw = (float)v.w * I16_INV;
    float w0 = w0s[m], w1 = w1s[m];
    a0.x += vx * w0; a0.y += vy * w0; a0.z += vz * w0; a0.w += vw * w0;
    a1.x += vx * w1; a1.y += vy * w1; a1.z += vz * w1; a1.w += vw * w1;
  }
  float v0[4] = {a0.x, a0.y, a0.z, a0.w};
  float v1[4] = {a1.x, a1.y, a1.z, a1.w};
  unsigned short h0[4], l0[4], h1v[4], l1v[4];
  #pragma unroll
  for (int k = 0; k < 4; ++k) {
    h0[k] = f2bf(v0[k]); l0[k] = f2bf(v0[k] - bf2f(h0[k]));
    h1v[k] = f2bf(v1[k]); l1v[k] = f2bf(v1[k] - bf2f(h1v[k]));
  }
  size_t o0 = (size_t)b * 2048 + tid * 4;
  size_t o1 = o0 + 1024;
  *(ushort4*)(Xhi + o0) = make_ushort4(h0[0], h0[1], h0[2], h0[3]);
  *(ushort4*)(Xlo + o0) = make_ushort4(l0[0], l0[1], l0[2], l0[3]);
  *(ushort4*)(Xhi + o1) = make_ushort4(h1v[0], h1v[1], h1v[2], h1v[3]);
  *(ushort4*)(Xlo + o1) = make_ushort4(l1v[0], l1v[1], l1v[2], l1v[3]);
}

// ---------------------------------------------------------------------------
extern "C" void kernel_launch(void* const* d_in, const int* in_sizes, int n_in,
                              void* d_out, int out_size, void* d_ws, size_t ws_size,
                              hipStream_t stream) {
  const float* x       = (const float*)d_in[0];
  const float* conv1_w = (const float*)d_in[1];
  const float* conv1_b = (const float*)d_in[2];
  const float* conv2_w = (const float*)d_in[3];
  const float* conv2_b = (const float*)d_in[4];
  const float* lin3_w  = (const float*)d_in[5];
  const float* lin3_b  = (const float*)d_in[6];
  const float* enc_Wih = (const float*)d_in[7];
  const float* enc_Whh = (const float*)d_in[8];
  const float* enc_b   = (const float*)d_in[9];
  const float* attn_Wq = (const float*)d_in[10];
  const float* attn_Wk = (const float*)d_in[11];
  const float* attn_Wv = (const float*)d_in[12];
  const float* dec_Wih = (const float*)d_in[13];
  const float* dec_Whh = (const float*)d_in[14];
  const float* dec_b   = (const float*)d_in[15];
  const float* out_w   = (const float*)d_in[16];
  const float* out_b   = (const float*)d_in[17];
  float* out = (float*)d_out;

  // ---- workspace carve: 106,102,784 B total (byte-identical to round 4) ----
  unsigned short* W = (unsigned short*)d_ws;
  short*          buf    = (short*)W;                  // 19,791,872 i16
  unsigned short* kp     = W + (size_t)19791872;       // 4,947,968
  unsigned short* qA_hi  = kp + 4947968;               // 262,144
  unsigned short* qA_lo  = qA_hi + 262144;
  unsigned short* qB_hi  = qA_lo + 262144;
  unsigned short* qB_lo  = qB_hi + 262144;
  unsigned short* Xc_hi  = qB_lo + 262144;             // 262,144
  unsigned short* Xc_lo  = Xc_hi + 262144;
  unsigned short* Wqk_hi = Xc_lo + 262144;             // 524,288
  unsigned short* Wqk_lo = Wqk_hi + 524288;
  unsigned short* Wdh_hi = Wqk_lo + 524288;            // 4,194,304 (enc Whh first)
  unsigned short* Wdh_lo = Wdh_hi + 4194304;
  unsigned short* Wdx_hi = Wdh_lo + 4194304;           // 8,388,608
  unsigned short* Wdx_lo = Wdx_hi + 8388608;           // 8,388,608
  float* c     = (float*)(Wdx_lo + 8388608);           // 131,072 f
  float* qkout = c + 131072;                           // 131,072 f
  // encoder-phase overlays (dead before Wdx conversion):
  unsigned short* h_hi0 = Wdx_hi;                      // 131,072
  unsigned short* h_hi1 = Wdx_hi + 131072;
  unsigned short* h_lo0 = Wdx_hi + 262144;
  unsigned short* h_lo1 = Wdx_hi + 393216;
  float* lstm_in = (float*)Wdx_lo;                     // 294,912 f

  init_all<<<512, 256, 0, stream>>>(c, h_hi0, h_lo0, out);
  conv_front<<<NB, 128, 0, stream>>>(x, conv1_w, conv1_b, conv2_w, conv2_b,
                                     lin3_w, lin3_b, lstm_in);
  split_bf<<<16384, 256, 0, stream>>>(enc_Whh, Wdh_hi, Wdh_lo, 4194304);
  split_bf<<<1024, 256, 0, stream>>>(attn_Wq, Wqk_hi, Wqk_lo, 262144);
  split_bf<<<1024, 256, 0, stream>>>(attn_Wk, Wqk_hi + 262144, Wqk_lo + 262144, 262144);

  // Encoder: bf16 hi/lo ping-pong recurrence; buf rows written i16
  for (int t = 0; t < NL; ++t) {
    const unsigned short* ih = (t & 1) ? h_hi1 : h_hi0;
    const unsigned short* il = (t & 1) ? h_lo1 : h_lo0;
    unsigned short* oh = (t & 1) ? h_hi0 : h_hi1;
    unsigned short* ol = (t & 1) ? h_lo0 : h_lo1;
    enc_step<<<128, 256, 0, stream>>>(ih, il, oh, ol, Wdh_hi, Wdh_lo,
                                      enc_Wih, enc_b, lstm_in, c, buf, t);
  }
  // t=127 (odd) wrote h_hi0/h_lo0 -> final h there

  dec_prep<<<NB, 256, 0, stream>>>(h_hi0, h_lo0, c, qA_hi, qA_lo);
  gemm_kp<<<dim3(302, 4), 256, 0, stream>>>(buf, Wqk_hi + 262144,
                                            Wqk_lo + 262144, kp);

  // decoder weights (overwrite encoder overlays — encoder + dec_prep done)
  split_bf<<<32768, 256, 0, stream>>>(dec_Wih, Wdx_hi, Wdx_lo, 8388608);
  split_bf<<<16384, 256, 0, stream>>>(dec_Whh, Wdh_hi, Wdh_lo, 4194304);

  for (int t = 0; t < NT; ++t) {
    const unsigned short* qih = (t & 1) ? qB_hi : qA_hi;
    const unsigned short* qil = (t & 1) ? qB_lo : qA_lo;
    unsigned short* qoh = (t & 1) ? qA_hi : qB_hi;
    unsigned short* qol = (t & 1) ? qA_lo : qB_lo;
    gemm_qk<<<dim3(4, 8), 256, 0, stream>>>(qih, qil, Wqk_hi, Wqk_lo, qkout);
    attn_kernel<<<NB, 256, 0, stream>>>(qkout, kp, buf, attn_Wv, Xc_hi, Xc_lo, t);
    dec_step<<<128, 256, 0, stream>>>(Xc_hi, Xc_lo, qih, qil, qoh, qol,
                                      Wdx_hi, Wdx_lo, Wdh_hi, Wdh_lo,
                                      dec_b, c, buf, out_w, out_b, out, t);
  }
}

// Round 7
// 8583.482 us; speedup vs baseline: 1.7834x; 1.0939x over previous
//
#include <hip/hip_runtime.h>
#include <math.h>

// Round 7: latency-hiding restructure (numerics of round 6 kept intact).
// - enc_step/dec_step: 512 threads = 8 waves, K-split x2 across wave-groups,
//   LDS partial-G reduce -> 2x waves/CU for latency hiding.
// - x-part (K=18, pad 32) folded into the encoder MFMA as hi/lo operands
//   (pre-staged xs/Wx); removes 288 scalar loads+FMAs per thread per step.
// - gemm_qk re-tiled 32x32 -> 128 blocks (was 32).
// - gemm_kp: single-bf16 A, 2-term (kp error is softmax-cancelled; r4 data).
// - attn: kp reads vectorized (ushort4).
// - dec_step: atomics halved via shfl pair-reduce.
// ws layout byte-identical to round 6 (106,102,784 B).

#define NB 128
#define NL 128
#define NH 1024
#define NA 256
#define NT 24
#define NM 151

typedef __attribute__((ext_vector_type(8))) short bf16x8;
typedef __attribute__((ext_vector_type(8))) short s16x8;
typedef __attribute__((ext_vector_type(4))) float f32x4;

#define MFMA(a, b, acc) __builtin_amdgcn_mfma_f32_16x16x32_bf16(a, b, acc, 0, 0, 0)

#define I16_SCALE 32767.0f
#define I16_INV   (1.0f / 32767.0f)

__device__ __forceinline__ float sig_f(float x) {
  return 1.0f / (1.0f + __expf(-x));
}
__device__ __forceinline__ float tanh_f(float x) {
  x = fminf(9.0f, fmaxf(-9.0f, x));
  float e = __expf(2.0f * x);
  return (e - 1.0f) / (e + 1.0f);
}
__device__ __forceinline__ unsigned short f2bf(float f) {
  unsigned int u = __float_as_uint(f);
  u = (u + 0x7FFFu + ((u >> 16) & 1u)) >> 16;
  return (unsigned short)u;
}
__device__ __forceinline__ float bf2f(unsigned short u) {
  return __uint_as_float(((unsigned int)u) << 16);
}
__device__ __forceinline__ short f2i16(float f) {
  return (short)__float2int_rn(f * I16_SCALE);
}

// ---------------------------------------------------------------------------
// conv front (proven round 1)
// ---------------------------------------------------------------------------
__global__ __launch_bounds__(128) void conv_front(
    const float* __restrict__ x,
    const float* __restrict__ w1, const float* __restrict__ b1,
    const float* __restrict__ w2, const float* __restrict__ b2,
    const float* __restrict__ w3, const float* __restrict__ b3,
    float* __restrict__ lstm_in)
{
  int b = blockIdx.x;
  int t = threadIdx.x;
  __shared__ float d[128][36];
  __shared__ float h1[128][34];
  __shared__ float h2[128][32];

  const float* xr = x + (size_t)(b * NL + t) * 48;
  #pragma unroll
  for (int f = 0; f < 36; ++f) d[t][f] = xr[f];
  __syncthreads();

  float acc[34];
  {
    float bias = b1[t];
    #pragma unroll
    for (int w = 0; w < 34; ++w) acc[w] = bias;
  }
  const float* wr = w1 + t * 384;
  for (int ci = 0; ci < 128; ++ci) {
    float row[36];
    #pragma unroll
    for (int f = 0; f < 36; ++f) row[f] = d[ci][f];
    float wa = wr[ci * 3 + 0], wb = wr[ci * 3 + 1], wc = wr[ci * 3 + 2];
    #pragma unroll
    for (int w = 0; w < 34; ++w)
      acc[w] += row[w] * wa + row[w + 1] * wb + row[w + 2] * wc;
  }
  #pragma unroll
  for (int w = 0; w < 34; ++w) {
    float z = acc[w];
    h1[t][w] = (z > 20.0f) ? z : log1pf(__expf(z));
  }
  __syncthreads();

  float acc2[32];
  {
    float bias = b2[t];
    #pragma unroll
    for (int w = 0; w < 32; ++w) acc2[w] = bias;
  }
  const float* wr2 = w2 + t * 384;
  for (int ci = 0; ci < 128; ++ci) {
    float row[34];
    #pragma unroll
    for (int f = 0; f < 34; ++f) row[f] = h1[ci][f];
    float wa = wr2[ci * 3 + 0], wb = wr2[ci * 3 + 1], wc = wr2[ci * 3 + 2];
    #pragma unroll
    for (int w = 0; w < 32; ++w)
      acc2[w] += row[w] * wa + row[w + 1] * wb + row[w + 2] * wc;
  }
  #pragma unroll
  for (int w = 0; w < 32; ++w) h2[t][w] = fmaxf(acc2[w], 0.0f);
  __syncthreads();

  float* outr = lstm_in + (size_t)(b * NL + t) * 18;
  #pragma unroll
  for (int e = 0; e < 6; ++e) {
    float s = b3[e];
    #pragma unroll
    for (int f = 0; f < 32; ++f) s += h2[t][f] * w3[e * 32 + f];
    outr[e] = s;
  }
  #pragma unroll
  for (int j = 0; j < 12; ++j) outr[6 + j] = xr[36 + j];
}

// ---------------------------------------------------------------------------
// conversion / init
// ---------------------------------------------------------------------------
__global__ void split_bf(const float* __restrict__ src,
                         unsigned short* __restrict__ hi,
                         unsigned short* __restrict__ lo, int n) {
  int i = blockIdx.x * 256 + threadIdx.x;
  if (i < n) {
    float v = src[i];
    unsigned short h = f2bf(v);
    hi[i] = h;
    lo[i] = f2bf(v - bf2f(h));
  }
}

// xs[b][t][0..32) = lstm_in[b][t][f] (f<18) else 0 ; hi/lo split
__global__ void build_xs(const float* __restrict__ lstm_in,
                         unsigned short* __restrict__ hi,
                         unsigned short* __restrict__ lo) {
  int i = blockIdx.x * 256 + threadIdx.x;
  if (i >= NB * NL * 32) return;
  int b = i >> 12;          // /4096
  int rem = i & 4095;
  int t = rem >> 5;
  int f = rem & 31;
  float v = (f < 18) ? lstm_in[(size_t)(b * NL + t) * 18 + f] : 0.0f;
  unsigned short h = f2bf(v);
  hi[i] = h;
  lo[i] = f2bf(v - bf2f(h));
}

// Wx[row][0..32) = enc_Wih[row][f] (f<18) else 0 ; hi/lo split
__global__ void build_wx(const float* __restrict__ wih,
                         unsigned short* __restrict__ hi,
                         unsigned short* __restrict__ lo) {
  int i = blockIdx.x * 256 + threadIdx.x;
  if (i >= 4096 * 32) return;
  int row = i >> 5;
  int f = i & 31;
  float v = (f < 18) ? wih[(size_t)row * 18 + f] : 0.0f;
  unsigned short h = f2bf(v);
  hi[i] = h;
  lo[i] = f2bf(v - bf2f(h));
}

__global__ void init_all(float* __restrict__ c,
                         unsigned short* __restrict__ hhi0,
                         unsigned short* __restrict__ hlo0,
                         float* __restrict__ out) {
  int i = blockIdx.x * 256 + threadIdx.x;
  if (i < NB * NH) { c[i] = 0.0f; hhi0[i] = 0; hlo0[i] = 0; }
  if (i < NB * NT) out[i] = 0.0f;
}

// ---------------------------------------------------------------------------
// Encoder step: gates = [h|x] @ [Whh|Wx]^T (split 3-term) + b; cell.
// 512 threads = 8 waves; wave-group grp (0/1) handles K-half; group 0 also
// does the x iter. LDS partial G[2], reduced in epilogue (tid<256).
// ---------------------------------------------------------------------------
__global__ __launch_bounds__(512) void enc_step(
    const unsigned short* __restrict__ hhi_in,
    const unsigned short* __restrict__ hlo_in,
    unsigned short* __restrict__ hhi_out,
    unsigned short* __restrict__ hlo_out,
    const unsigned short* __restrict__ Whh_hi,
    const unsigned short* __restrict__ Whh_lo,
    const unsigned short* __restrict__ Wx_hi,
    const unsigned short* __restrict__ Wx_lo,
    const unsigned short* __restrict__ xs_hi,
    const unsigned short* __restrict__ xs_lo,
    const float* __restrict__ encb,
    float* __restrict__ c,
    short* __restrict__ buf,
    int t)
{
  __shared__ float G[2][128][33];
  int tid = threadIdx.x;
  int w8 = tid >> 6, lane = tid & 63;
  int grp = w8 >> 2, wm = w8 & 3;
  int l15 = lane & 15, q8 = (lane >> 4) * 8, q4 = (lane >> 4) * 4;
  int c0 = blockIdx.x * 8;

  size_t r0 = (size_t)((l15 >> 3) * NH + c0 + (l15 & 7));
  size_t r1 = (size_t)(((l15 >> 3) + 2) * NH + c0 + (l15 & 7));
  const unsigned short* B0h = Whh_hi + r0 * NH;
  const unsigned short* B1h = Whh_hi + r1 * NH;
  const unsigned short* B0l = Whh_lo + r0 * NH;
  const unsigned short* B1l = Whh_lo + r1 * NH;
  size_t ar0 = (size_t)(32 * wm + l15) * NH;
  size_t ar1 = (size_t)(32 * wm + 16 + l15) * NH;
  const unsigned short* A0h = hhi_in + ar0;
  const unsigned short* A1h = hhi_in + ar1;
  const unsigned short* A0l = hlo_in + ar0;
  const unsigned short* A1l = hlo_in + ar1;

  int kbase = grp * 512;
  f32x4 a00 = {0,0,0,0}, a01 = {0,0,0,0}, a10 = {0,0,0,0}, a11 = {0,0,0,0};
  for (int k0 = 0; k0 < 512; k0 += 32) {
    int ko = kbase + k0 + q8;
    bf16x8 x0h = *(const bf16x8*)(A0h + ko);
    bf16x8 x0l = *(const bf16x8*)(A0l + ko);
    bf16x8 x1h = *(const bf16x8*)(A1h + ko);
    bf16x8 x1l = *(const bf16x8*)(A1l + ko);
    bf16x8 y0h = *(const bf16x8*)(B0h + ko);
    bf16x8 y0l = *(const bf16x8*)(B0l + ko);
    bf16x8 y1h = *(const bf16x8*)(B1h + ko);
    bf16x8 y1l = *(const bf16x8*)(B1l + ko);
    a00 = MFMA(x0h, y0h, a00); a00 = MFMA(x0l, y0h, a00); a00 = MFMA(x0h, y0l, a00);
    a01 = MFMA(x0h, y1h, a01); a01 = MFMA(x0l, y1h, a01); a01 = MFMA(x0h, y1l, a01);
    a10 = MFMA(x1h, y0h, a10); a10 = MFMA(x1l, y0h, a10); a10 = MFMA(x1h, y0l, a10);
    a11 = MFMA(x1h, y1h, a11); a11 = MFMA(x1l, y1h, a11); a11 = MFMA(x1h, y1l, a11);
  }
  if (grp == 0) {
    // x iter (K=32 padded): A from xs, B from Wx
    size_t xo0 = (size_t)(32 * wm + l15) * 4096 + t * 32 + q8;
    size_t xo1 = (size_t)(32 * wm + 16 + l15) * 4096 + t * 32 + q8;
    bf16x8 x0h = *(const bf16x8*)(xs_hi + xo0);
    bf16x8 x0l = *(const bf16x8*)(xs_lo + xo0);
    bf16x8 x1h = *(const bf16x8*)(xs_hi + xo1);
    bf16x8 x1l = *(const bf16x8*)(xs_lo + xo1);
    bf16x8 y0h = *(const bf16x8*)(Wx_hi + r0 * 32 + q8);
    bf16x8 y0l = *(const bf16x8*)(Wx_lo + r0 * 32 + q8);
    bf16x8 y1h = *(const bf16x8*)(Wx_hi + r1 * 32 + q8);
    bf16x8 y1l = *(const bf16x8*)(Wx_lo + r1 * 32 + q8);
    a00 = MFMA(x0h, y0h, a00); a00 = MFMA(x0l, y0h, a00); a00 = MFMA(x0h, y0l, a00);
    a01 = MFMA(x0h, y1h, a01); a01 = MFMA(x0l, y1h, a01); a01 = MFMA(x0h, y1l, a01);
    a10 = MFMA(x1h, y0h, a10); a10 = MFMA(x1l, y0h, a10); a10 = MFMA(x1h, y0l, a10);
    a11 = MFMA(x1h, y1h, a11); a11 = MFMA(x1l, y1h, a11); a11 = MFMA(x1h, y1l, a11);
  }
  #pragma unroll
  for (int r = 0; r < 4; ++r) {
    G[grp][32 * wm + q4 + r][l15]           = a00[r];
    G[grp][32 * wm + q4 + r][16 + l15]      = a01[r];
    G[grp][32 * wm + 16 + q4 + r][l15]      = a10[r];
    G[grp][32 * wm + 16 + q4 + r][16 + l15] = a11[r];
  }
  __syncthreads();

  if (tid < 256) {
    int b = tid >> 1;
    int cc0 = (tid & 1) * 4;
    float4 cold = *(const float4*)(c + (size_t)b * NH + c0 + cc0);
    float rc[4], rh[4];
    #pragma unroll
    for (int j = 0; j < 4; ++j) {
      int cc = cc0 + j;
      float gate[4];
      #pragma unroll
      for (int q = 0; q < 4; ++q) {
        int gi = q * 8 + cc;
        gate[q] = G[0][b][gi] + G[1][b][gi] + encb[q * NH + c0 + cc];
      }
      float co = (&cold.x)[j];
      float cn = sig_f(gate[1]) * co + sig_f(gate[0]) * tanh_f(gate[2]);
      float hn = sig_f(gate[3]) * tanh_f(cn);
      rc[j] = cn; rh[j] = hn;
    }
    *(float4*)(c + (size_t)b * NH + c0 + cc0) =
        make_float4(rc[0], rc[1], rc[2], rc[3]);
    unsigned short hh[4], hl[4];
    short hq[4];
    #pragma unroll
    for (int j = 0; j < 4; ++j) {
      hh[j] = f2bf(rh[j]);
      hl[j] = f2bf(rh[j] - bf2f(hh[j]));
      hq[j] = f2i16(rh[j]);
    }
    size_t hoff = (size_t)b * NH + c0 + cc0;
    *(ushort4*)(hhi_out + hoff) = make_ushort4(hh[0], hh[1], hh[2], hh[3]);
    *(ushort4*)(hlo_out + hoff) = make_ushort4(hl[0], hl[1], hl[2], hl[3]);
    *(short4*)(buf + (size_t)(b * NM + t) * NH + c0 + cc0) =
        make_short4(hq[0], hq[1], hq[2], hq[3]);
  }
}

// ---------------------------------------------------------------------------
// Decoder step: gates = ctx@Wdx^T (3-term, K=2048) + h@Wdh^T (3-term, K=1024)
// + b; cell; y. 512 threads, K-split: grp0 = ctx[0,1536); grp1 = ctx[1536,
// 2048) + h. LDS partial G[2].
// ---------------------------------------------------------------------------
__global__ __launch_bounds__(512) void dec_step(
    const unsigned short* __restrict__ Xhi,
    const unsigned short* __restrict__ Xlo,
    const unsigned short* __restrict__ qin_hi,
    const unsigned short* __restrict__ qin_lo,
    unsigned short* __restrict__ qout_hi,
    unsigned short* __restrict__ qout_lo,
    const unsigned short* __restrict__ Wdx_hi,
    const unsigned short* __restrict__ Wdx_lo,
    const unsigned short* __restrict__ Wdh_hi,
    const unsigned short* __restrict__ Wdh_lo,
    const float* __restrict__ decb,
    float* __restrict__ c,
    short* __restrict__ buf,
    const float* __restrict__ out_w, const float* __restrict__ out_b,
    float* __restrict__ out, int t)
{
  __shared__ float G[2][128][33];
  int tid = threadIdx.x;
  int w8 = tid >> 6, lane = tid & 63;
  int grp = w8 >> 2, wm = w8 & 3;
  int l15 = lane & 15, q8 = (lane >> 4) * 8, q4 = (lane >> 4) * 4;
  int c0 = blockIdx.x * 8;

  size_t r0 = (size_t)((l15 >> 3) * NH + c0 + (l15 & 7));
  size_t r1 = (size_t)(((l15 >> 3) + 2) * NH + c0 + (l15 & 7));

  f32x4 a00 = {0,0,0,0}, a01 = {0,0,0,0}, a10 = {0,0,0,0}, a11 = {0,0,0,0};

  // ctx phase
  {
    size_t xr0 = (size_t)(32 * wm + l15) * 2048;
    size_t xr1 = (size_t)(32 * wm + 16 + l15) * 2048;
    const unsigned short* X0h = Xhi + xr0;
    const unsigned short* X1h = Xhi + xr1;
    const unsigned short* X0l = Xlo + xr0;
    const unsigned short* X1l = Xlo + xr1;
    const unsigned short* W0h = Wdx_hi + r0 * 2048;
    const unsigned short* W1h = Wdx_hi + r1 * 2048;
    const unsigned short* W0l = Wdx_lo + r0 * 2048;
    const unsigned short* W1l = Wdx_lo + r1 * 2048;
    int kc_lo = grp ? 1536 : 0;
    int kc_hi = grp ? 2048 : 1536;
    for (int k0 = kc_lo; k0 < kc_hi; k0 += 32) {
      int ko = k0 + q8;
      bf16x8 x0h = *(const bf16x8*)(X0h + ko);
      bf16x8 x0l = *(const bf16x8*)(X0l + ko);
      bf16x8 x1h = *(const bf16x8*)(X1h + ko);
      bf16x8 x1l = *(const bf16x8*)(X1l + ko);
      bf16x8 y0h = *(const bf16x8*)(W0h + ko);
      bf16x8 y0l = *(const bf16x8*)(W0l + ko);
      bf16x8 y1h = *(const bf16x8*)(W1h + ko);
      bf16x8 y1l = *(const bf16x8*)(W1l + ko);
      a00 = MFMA(x0h, y0h, a00); a00 = MFMA(x0l, y0h, a00); a00 = MFMA(x0h, y0l, a00);
      a01 = MFMA(x0h, y1h, a01); a01 = MFMA(x0l, y1h, a01); a01 = MFMA(x0h, y1l, a01);
      a10 = MFMA(x1h, y0h, a10); a10 = MFMA(x1l, y0h, a10); a10 = MFMA(x1h, y0l, a10);
      a11 = MFMA(x1h, y1h, a11); a11 = MFMA(x1l, y1h, a11); a11 = MFMA(x1h, y1l, a11);
    }
  }
  // h phase (group 1 only)
  if (grp) {
    size_t ar0 = (size_t)(2 * (32 * wm + l15)) * NH;
    size_t ar1 = (size_t)(2 * (32 * wm + 16 + l15)) * NH;
    const unsigned short* A0h = qin_hi + ar0;
    const unsigned short* A1h = qin_hi + ar1;
    const unsigned short* A0l = qin_lo + ar0;
    const unsigned short* A1l = qin_lo + ar1;
    const unsigned short* B0h = Wdh_hi + r0 * NH;
    const unsigned short* B1h = Wdh_hi + r1 * NH;
    const unsigned short* B0l = Wdh_lo + r0 * NH;
    const unsigned short* B1l = Wdh_lo + r1 * NH;
    for (int k0 = 0; k0 < NH; k0 += 32) {
      int ko = k0 + q8;
      bf16x8 x0h = *(const bf16x8*)(A0h + ko);
      bf16x8 x0l = *(const bf16x8*)(A0l + ko);
      bf16x8 x1h = *(const bf16x8*)(A1h + ko);
      bf16x8 x1l = *(const bf16x8*)(A1l + ko);
      bf16x8 y0h = *(const bf16x8*)(B0h + ko);
      bf16x8 y0l = *(const bf16x8*)(B0l + ko);
      bf16x8 y1h = *(const bf16x8*)(B1h + ko);
      bf16x8 y1l = *(const bf16x8*)(B1l + ko);
      a00 = MFMA(x0h, y0h, a00); a00 = MFMA(x0l, y0h, a00); a00 = MFMA(x0h, y0l, a00);
      a01 = MFMA(x0h, y1h, a01); a01 = MFMA(x0l, y1h, a01); a01 = MFMA(x0h, y1l, a01);
      a10 = MFMA(x1h, y0h, a10); a10 = MFMA(x1l, y0h, a10); a10 = MFMA(x1h, y0l, a10);
      a11 = MFMA(x1h, y1h, a11); a11 = MFMA(x1l, y1h, a11); a11 = MFMA(x1h, y1l, a11);
    }
  }
  #pragma unroll
  for (int r = 0; r < 4; ++r) {
    G[grp][32 * wm + q4 + r][l15]           = a00[r];
    G[grp][32 * wm + q4 + r][16 + l15]      = a01[r];
    G[grp][32 * wm + 16 + q4 + r][l15]      = a10[r];
    G[grp][32 * wm + 16 + q4 + r][16 + l15] = a11[r];
  }
  __syncthreads();

  if (tid < 256) {
    int b = tid >> 1;
    int cc0 = (tid & 1) * 4;
    float4 cold = *(const float4*)(c + (size_t)b * NH + c0 + cc0);
    float rc[4], rh[4];
    #pragma unroll
    for (int j = 0; j < 4; ++j) {
      int cc = cc0 + j;
      float gate[4];
      #pragma unroll
      for (int q = 0; q < 4; ++q) {
        int gi = q * 8 + cc;
        gate[q] = G[0][b][gi] + G[1][b][gi] + decb[q * NH + c0 + cc];
      }
      float co = (&cold.x)[j];
      float cn = sig_f(gate[1]) * co + sig_f(gate[0]) * tanh_f(gate[2]);
      float hn = sig_f(gate[3]) * tanh_f(cn);
      rc[j] = cn; rh[j] = hn;
    }
    *(float4*)(c + (size_t)b * NH + c0 + cc0) =
        make_float4(rc[0], rc[1], rc[2], rc[3]);

    float py = 0.0f;
    #pragma unroll
    for (int j = 0; j < 4; ++j) py += rh[j] * out_w[c0 + cc0 + j];
    if (blockIdx.x == 0 && (tid & 1) == 0) py += out_b[0];
    py += __shfl_down(py, 1);
    if ((tid & 1) == 0) atomicAdd(&out[b * NT + t], py);

    if (t < NT - 1) {
      unsigned short hh[4], hl[4], ch[4], cl[4];
      short hq[4];
      #pragma unroll
      for (int j = 0; j < 4; ++j) {
        hh[j] = f2bf(rh[j]); hl[j] = f2bf(rh[j] - bf2f(hh[j]));
        ch[j] = f2bf(rc[j]); cl[j] = f2bf(rc[j] - bf2f(ch[j]));
        hq[j] = f2i16(rh[j]);
      }
      *(short4*)(buf + (size_t)(b * NM + NL + t) * NH + c0 + cc0) =
          make_short4(hq[0], hq[1], hq[2], hq[3]);
      size_t qh = (size_t)(2 * b) * NH + c0 + cc0;
      size_t qc = (size_t)(2 * b + 1) * NH + c0 + cc0;
      *(ushort4*)(qout_hi + qh) = make_ushort4(hh[0], hh[1], hh[2], hh[3]);
      *(ushort4*)(qout_lo + qh) = make_ushort4(hl[0], hl[1], hl[2], hl[3]);
      *(ushort4*)(qout_hi + qc) = make_ushort4(ch[0], ch[1], ch[2], ch[3]);
      *(ushort4*)(qout_lo + qc) = make_ushort4(cl[0], cl[1], cl[2], cl[3]);
    }
  }
}

// dec_prep: h from dedicated hi/lo buffers, c fp32 -> q rows.
__global__ __launch_bounds__(256) void dec_prep(
    const unsigned short* __restrict__ hhi,
    const unsigned short* __restrict__ hlo,
    const float* __restrict__ c,
    unsigned short* __restrict__ qhi, unsigned short* __restrict__ qlo)
{
  int b = blockIdx.x;
  int j = threadIdx.x * 4;
  ushort4 hv = *(const ushort4*)(hhi + (size_t)b * NH + j);
  ushort4 lv = *(const ushort4*)(hlo + (size_t)b * NH + j);
  float4 cv = *(const float4*)(c + (size_t)b * NH + j);
  unsigned short ch[4], cl[4];
  float cf[4] = {cv.x, cv.y, cv.z, cv.w};
  #pragma unroll
  for (int k = 0; k < 4; ++k) {
    ch[k] = f2bf(cf[k]); cl[k] = f2bf(cf[k] - bf2f(ch[k]));
  }
  *(ushort4*)(qhi + (size_t)(2 * b) * NH + j) = hv;
  *(ushort4*)(qlo + (size_t)(2 * b) * NH + j) = lv;
  *(ushort4*)(qhi + (size_t)(2 * b + 1) * NH + j) = make_ushort4(ch[0], ch[1], ch[2], ch[3]);
  *(ushort4*)(qlo + (size_t)(2 * b + 1) * NH + j) = make_ushort4(cl[0], cl[1], cl[2], cl[3]);
}

// ---------------------------------------------------------------------------
// q/k projections, split 3-term, 32x32 tiles: grid(8,16), 256 threads.
// qkout[256,512] = qbuf[256,1024] @ Wqk[512,1024]^T.
// ---------------------------------------------------------------------------
__global__ __launch_bounds__(256) void gemm_qk(
    const unsigned short* __restrict__ Ahi, const unsigned short* __restrict__ Alo,
    const unsigned short* __restrict__ Bhi, const unsigned short* __restrict__ Blo,
    float* __restrict__ C)
{
  int tid = threadIdx.x;
  int w = tid >> 6, lane = tid & 63;
  int l15 = lane & 15, q8 = (lane >> 4) * 8, q4 = (lane >> 4) * 4;
  int m0 = blockIdx.x * 32 + (w >> 1) * 16;
  int n0 = blockIdx.y * 32 + (w & 1) * 16;

  const unsigned short* Ah = Ahi + (size_t)(m0 + l15) * NH;
  const unsigned short* Al = Alo + (size_t)(m0 + l15) * NH;
  const unsigned short* Bh = Bhi + (size_t)(n0 + l15) * NH;
  const unsigned short* Bl = Blo + (size_t)(n0 + l15) * NH;
  f32x4 acc = {0, 0, 0, 0};
  for (int k0 = 0; k0 < NH; k0 += 32) {
    int ko = k0 + q8;
    bf16x8 ah = *(const bf16x8*)(Ah + ko);
    bf16x8 al = *(const bf16x8*)(Al + ko);
    bf16x8 bh = *(const bf16x8*)(Bh + ko);
    bf16x8 bl = *(const bf16x8*)(Bl + ko);
    acc = MFMA(ah, bh, acc);
    acc = MFMA(al, bh, acc);
    acc = MFMA(ah, bl, acc);
  }
  #pragma unroll
  for (int r = 0; r < 4; ++r)
    C[(size_t)(m0 + q4 + r) * 512 + n0 + l15] = acc[r];
}

// ---------------------------------------------------------------------------
// Bulk kp: kp = buf(i16) @ Wk^T. A converted i16->bf16 (single, RN) in regs;
// 2-term on B (kp error softmax-cancelled). grid(302,4).
// ---------------------------------------------------------------------------
__global__ __launch_bounds__(256) void gemm_kp(
    const short* __restrict__ A,
    const unsigned short* __restrict__ Bhi,
    const unsigned short* __restrict__ Blo,
    unsigned short* __restrict__ C)
{
  int tid = threadIdx.x;
  int w = tid >> 6, lane = tid & 63;
  int l15 = lane & 15, q8 = (lane >> 4) * 8, q4 = (lane >> 4) * 4;
  size_t m0 = (size_t)blockIdx.x * 64;
  int n0 = blockIdx.y * 64 + w * 16;

  const unsigned short* Bh = Bhi + (size_t)(n0 + l15) * NH;
  const unsigned short* Bl = Blo + (size_t)(n0 + l15) * NH;
  f32x4 acc[4] = {{0,0,0,0},{0,0,0,0},{0,0,0,0},{0,0,0,0}};
  for (int k0 = 0; k0 < NH; k0 += 32) {
    int ko = k0 + q8;
    bf16x8 bh = *(const bf16x8*)(Bh + ko);
    bf16x8 bl = *(const bf16x8*)(Bl + ko);
    #pragma unroll
    for (int i = 0; i < 4; ++i) {
      s16x8 av = *(const s16x8*)(A + (m0 + 16 * i + l15) * (size_t)NH + ko);
      bf16x8 ah;
      #pragma unroll
      for (int k = 0; k < 8; ++k)
        ah[k] = (short)f2bf((float)av[k] * I16_INV);
      acc[i] = MFMA(ah, bh, acc[i]);
      acc[i] = MFMA(ah, bl, acc[i]);
    }
  }
  #pragma unroll
  for (int i = 0; i < 4; ++i)
    #pragma unroll
    for (int r = 0; r < 4; ++r)
      C[(m0 + 16 * i + q4 + r) * NA + n0 + l15] = f2bf(acc[i][r]);
}

// ---------------------------------------------------------------------------
// Attention: scores (vectorized kp reads) + pairwise softmax over n; ctx
// accumulated fp32 from i16 buf; written hi/lo bf16 to Xc.
// ---------------------------------------------------------------------------
__global__ __launch_bounds__(256) void attn_kernel(
    const float* __restrict__ qkout,
    unsigned short* __restrict__ kp,
    const short* __restrict__ buf,
    const float* __restrict__ Wv,
    unsigned short* __restrict__ Xhi,
    unsigned short* __restrict__ Xlo,
    int t)
{
  int b = blockIdx.x;
  int tid = threadIdx.x;
  int Mt = NL + t;
  __shared__ float sWv[256], q0[256], q1[256], kNew[256];
  __shared__ float sc[2][NM + 1];
  __shared__ float w0s[NM + 1], w1s[NM + 1];
  sWv[tid] = Wv[tid];
  q0[tid] = qkout[(size_t)(2 * b) * 512 + tid];
  q1[tid] = qkout[(size_t)(2 * b + 1) * 512 + tid];
  float kn = qkout[(size_t)(2 * b) * 512 + 256 + tid];
  kNew[tid] = kn;
  kp[((size_t)(b * NM) + (NL - 1 + t)) * NA + tid] = f2bf(kn);
  __syncthreads();

  for (int idx = tid; idx < 2 * Mt; idx += 256) {
    int m = idx >> 1, n = idx & 1;
    const float* q = n ? q1 : q0;
    float s = 0.0f;
    if (m == Mt - 1) {
      for (int a = 0; a < NA; ++a) s += tanh_f(q[a] + kNew[a]) * sWv[a];
    } else {
      const unsigned short* kpr = kp + ((size_t)(b * NM) + m) * NA;
      for (int a = 0; a < NA; a += 4) {
        ushort4 kv = *(const ushort4*)(kpr + a);
        s += tanh_f(q[a + 0] + bf2f(kv.x)) * sWv[a + 0];
        s += tanh_f(q[a + 1] + bf2f(kv.y)) * sWv[a + 1];
        s += tanh_f(q[a + 2] + bf2f(kv.z)) * sWv[a + 2];
        s += tanh_f(q[a + 3] + bf2f(kv.w)) * sWv[a + 3];
      }
    }
    sc[n][m] = s;
  }
  __syncthreads();
  for (int m = tid; m < Mt; m += 256) {
    float s0 = sc[0][m], s1 = sc[1][m];
    float mx = fmaxf(s0, s1);
    float e0 = __expf(s0 - mx), e1 = __expf(s1 - mx);
    float inv = 1.0f / (e0 + e1);
    w0s[m] = e0 * inv;
    w1s[m] = e1 * inv;
  }
  __syncthreads();

  float4 a0 = {0, 0, 0, 0}, a1 = {0, 0, 0, 0};
  const short* bb = buf + ((size_t)b * NM) * NH + tid * 4;
  for (int m = 0; m < Mt; ++m) {
    short4 v = *(const short4*)(bb + (size_t)m * NH);
    float vx = (float)v.x * I16_INV, vy = (float)v.y * I16_INV;
    float vz = (float)v.z * I16_INV, vw = (float)v.w * I16_INV;
    float w0 = w0s[m], w1 = w1s[m];
    a0.x += vx * w0; a0.y += vy * w0; a0.z += vz * w0; a0.w += vw * w0;
    a1.x += vx * w1; a1.y += vy * w1; a1.z += vz * w1; a1.w += vw * w1;
  }
  float v0[4] = {a0.x, a0.y, a0.z, a0.w};
  float v1[4] = {a1.x, a1.y, a1.z, a1.w};
  unsigned short h0[4], l0[4], h1v[4], l1v[4];
  #pragma unroll
  for (int k = 0; k < 4; ++k) {
    h0[k] = f2bf(v0[k]); l0[k] = f2bf(v0[k] - bf2f(h0[k]));
    h1v[k] = f2bf(v1[k]); l1v[k] = f2bf(v1[k] - bf2f(h1v[k]));
  }
  size_t o0 = (size_t)b * 2048 + tid * 4;
  size_t o1 = o0 + 1024;
  *(ushort4*)(Xhi + o0) = make_ushort4(h0[0], h0[1], h0[2], h0[3]);
  *(ushort4*)(Xlo + o0) = make_ushort4(l0[0], l0[1], l0[2], l0[3]);
  *(ushort4*)(Xhi + o1) = make_ushort4(h1v[0], h1v[1], h1v[2], h1v[3]);
  *(ushort4*)(Xlo + o1) = make_ushort4(l1v[0], l1v[1], l1v[2], l1v[3]);
}

// ---------------------------------------------------------------------------
extern "C" void kernel_launch(void* const* d_in, const int* in_sizes, int n_in,
                              void* d_out, int out_size, void* d_ws, size_t ws_size,
                              hipStream_t stream) {
  const float* x       = (const float*)d_in[0];
  const float* conv1_w = (const float*)d_in[1];
  const float* conv1_b = (const float*)d_in[2];
  const float* conv2_w = (const float*)d_in[3];
  const float* conv2_b = (const float*)d_in[4];
  const float* lin3_w  = (const float*)d_in[5];
  const float* lin3_b  = (const float*)d_in[6];
  const float* enc_Wih = (const float*)d_in[7];
  const float* enc_Whh = (const float*)d_in[8];
  const float* enc_b   = (const float*)d_in[9];
  const float* attn_Wq = (const float*)d_in[10];
  const float* attn_Wk = (const float*)d_in[11];
  const float* attn_Wv = (const float*)d_in[12];
  const float* dec_Wih = (const float*)d_in[13];
  const float* dec_Whh = (const float*)d_in[14];
  const float* dec_b   = (const float*)d_in[15];
  const float* out_w   = (const float*)d_in[16];
  const float* out_b   = (const float*)d_in[17];
  float* out = (float*)d_out;

  // ---- workspace carve: 106,102,784 B (byte-identical to round 6) ----
  unsigned short* W = (unsigned short*)d_ws;
  short*          buf    = (short*)W;                  // 19,791,872 i16
  unsigned short* kp     = W + (size_t)19791872;       // 4,947,968
  unsigned short* qA_hi  = kp + 4947968;               // 262,144
  unsigned short* qA_lo  = qA_hi + 262144;
  unsigned short* qB_hi  = qA_lo + 262144;
  unsigned short* qB_lo  = qB_hi + 262144;
  unsigned short* Xc_hi  = qB_lo + 262144;             // 262,144
  unsigned short* Xc_lo  = Xc_hi + 262144;
  unsigned short* Wqk_hi = Xc_lo + 262144;             // 524,288
  unsigned short* Wqk_lo = Wqk_hi + 524288;
  unsigned short* Wdh_hi = Wqk_lo + 524288;            // 4,194,304 (enc Whh first)
  unsigned short* Wdh_lo = Wdh_hi + 4194304;
  unsigned short* Wdx_hi = Wdh_lo + 4194304;           // 8,388,608
  unsigned short* Wdx_lo = Wdx_hi + 8388608;           // 8,388,608
  float* c     = (float*)(Wdx_lo + 8388608);           // 131,072 f
  float* qkout = c + 131072;                           // 131,072 f
  // encoder-phase overlays in Wdx regions (dead until dec weight split):
  unsigned short* h_hi0 = Wdx_hi;                      // 131,072
  unsigned short* h_hi1 = Wdx_hi + 131072;
  unsigned short* h_lo0 = Wdx_hi + 262144;
  unsigned short* h_lo1 = Wdx_hi + 393216;
  unsigned short* xs_hi = Wdx_hi + 524288;             // 524,288
  unsigned short* xs_lo = xs_hi + 524288;              // 524,288
  unsigned short* Wx_hi = xs_lo + 524288;              // 131,072
  unsigned short* Wx_lo = Wx_hi + 131072;              // 131,072 (total 1.84M <= 8.38M)
  float* lstm_in = (float*)Wdx_lo;                     // 294,912 f

  init_all<<<512, 256, 0, stream>>>(c, h_hi0, h_lo0, out);
  conv_front<<<NB, 128, 0, stream>>>(x, conv1_w, conv1_b, conv2_w, conv2_b,
                                     lin3_w, lin3_b, lstm_in);
  build_xs<<<2048, 256, 0, stream>>>(lstm_in, xs_hi, xs_lo);
  build_wx<<<512, 256, 0, stream>>>(enc_Wih, Wx_hi, Wx_lo);
  split_bf<<<16384, 256, 0, stream>>>(enc_Whh, Wdh_hi, Wdh_lo, 4194304);
  split_bf<<<1024, 256, 0, stream>>>(attn_Wq, Wqk_hi, Wqk_lo, 262144);
  split_bf<<<1024, 256, 0, stream>>>(attn_Wk, Wqk_hi + 262144, Wqk_lo + 262144, 262144);

  // Encoder: bf16 hi/lo ping-pong recurrence; buf rows written i16
  for (int t = 0; t < NL; ++t) {
    const unsigned short* ih = (t & 1) ? h_hi1 : h_hi0;
    const unsigned short* il = (t & 1) ? h_lo1 : h_lo0;
    unsigned short* oh = (t & 1) ? h_hi0 : h_hi1;
    unsigned short* ol = (t & 1) ? h_lo0 : h_lo1;
    enc_step<<<128, 512, 0, stream>>>(ih, il, oh, ol, Wdh_hi, Wdh_lo,
                                      Wx_hi, Wx_lo, xs_hi, xs_lo,
                                      enc_b, c, buf, t);
  }
  // t=127 (odd) wrote h_hi0/h_lo0 -> final h there

  dec_prep<<<NB, 256, 0, stream>>>(h_hi0, h_lo0, c, qA_hi, qA_lo);
  gemm_kp<<<dim3(302, 4), 256, 0, stream>>>(buf, Wqk_hi + 262144,
                                            Wqk_lo + 262144, kp);

  // decoder weights (overwrite encoder overlays — encoder + dec_prep done)
  split_bf<<<32768, 256, 0, stream>>>(dec_Wih, Wdx_hi, Wdx_lo, 8388608);
  split_bf<<<16384, 256, 0, stream>>>(dec_Whh, Wdh_hi, Wdh_lo, 4194304);

  for (int t = 0; t < NT; ++t) {
    const unsigned short* qih = (t & 1) ? qB_hi : qA_hi;
    const unsigned short* qil = (t & 1) ? qB_lo : qA_lo;
    unsigned short* qoh = (t & 1) ? qA_hi : qB_hi;
    unsigned short* qol = (t & 1) ? qA_lo : qB_lo;
    gemm_qk<<<dim3(8, 16), 256, 0, stream>>>(qih, qil, Wqk_hi, Wqk_lo, qkout);
    attn_kernel<<<NB, 256, 0, stream>>>(qkout, kp, buf, attn_Wv, Xc_hi, Xc_lo, t);
    dec_step<<<128, 512, 0, stream>>>(Xc_hi, Xc_lo, qih, qil, qoh, qol,
                                      Wdx_hi, Wdx_lo, Wdh_hi, Wdh_lo,
                                      dec_b, c, buf, out_w, out_b, out, t);
  }
}